// Round 1
// baseline (271.547 us; speedup 1.0000x reference)
//
#include <hip/hip_runtime.h>

// ---------------------------------------------------------------- types
typedef __attribute__((ext_vector_type(8))) short bf16x8;   // 8 bf16 (4 VGPR)
typedef __attribute__((ext_vector_type(4))) float f32x4;
typedef __attribute__((ext_vector_type(2))) unsigned int u32x2;
typedef __attribute__((ext_vector_type(4))) unsigned int u32x4;

#define MFMA16(a, b, c) __builtin_amdgcn_mfma_f32_16x16x32_bf16((a), (b), (c), 0, 0, 0)

// B=4, S=2048, E=1024, H=16, D=64
#define S_LEN 2048
#define NHEAD 16
#define DHEAD 64
#define BH    64            // B*H
#define MROWS 8192          // B*S

__device__ __forceinline__ unsigned short f2bf(float f) {
  unsigned int u = __builtin_bit_cast(unsigned int, f);
  u += 0x7FFFu + ((u >> 16) & 1u);          // round-to-nearest-even
  return (unsigned short)(u >> 16);
}

__device__ __forceinline__ void gl_lds16(const void* g, void* l) {
  __builtin_amdgcn_global_load_lds(
      (const __attribute__((address_space(1))) void*)g,
      (__attribute__((address_space(3))) void*)l, 16, 0, 0);
}

// pack two fp32 -> (bf16(hi)<<16)|bf16(lo), round-half-up via add+perm
__device__ __forceinline__ unsigned int pkbf(float lo, float hi) {
  unsigned int ulo = __builtin_bit_cast(unsigned int, lo) + 0x8000u;
  unsigned int uhi = __builtin_bit_cast(unsigned int, hi) + 0x8000u;
  return __builtin_amdgcn_perm(uhi, ulo, 0x07060302u);
}

// ---------------------------------------------------------------- cast fp32 -> bf16
__global__ __launch_bounds__(256) void cast_bf16(const float* __restrict__ src,
                                                 unsigned short* __restrict__ dst, int n) {
  int i = (blockIdx.x * 256 + threadIdx.x) * 4;
  if (i + 3 < n) {
    f32x4 v = *(const f32x4*)(src + i);
    unsigned long long pk =
        (unsigned long long)f2bf(v[0]) |
        ((unsigned long long)f2bf(v[1]) << 16) |
        ((unsigned long long)f2bf(v[2]) << 32) |
        ((unsigned long long)f2bf(v[3]) << 48);
    *(unsigned long long*)(dst + i) = pk;
  }
}

// ---------------------------------------------------------------- transpose + cast (plain, for Wo)
__global__ __launch_bounds__(256) void transpose_cast(const float* __restrict__ src,
                                                      unsigned short* __restrict__ dst,
                                                      int R, int C) {
  __shared__ float tile[32][33];
  int c0 = blockIdx.x * 32, r0 = blockIdx.y * 32;
  int tx = threadIdx.x, ty = threadIdx.y;   // block (32,8)
  for (int i = 0; i < 32; i += 8)
    tile[ty + i][tx] = src[(size_t)(r0 + ty + i) * C + c0 + tx];
  __syncthreads();
  for (int i = 0; i < 32; i += 8)
    dst[(size_t)(c0 + ty + i) * R + r0 + tx] = f2bf(tile[tx][ty + i]);
}

// ---------------------------------------------------------------- transpose + cast + col-permute for Wqkv
// src [1024 k][3072 oc], oc = h*192 + which*64 + d  ->  dst[nc][1024], nc = which*1024 + h*64 + d
__global__ __launch_bounds__(256) void transpose_cast_qkv(const float* __restrict__ src,
                                                          unsigned short* __restrict__ dst) {
  __shared__ float tile[32][33];
  int c0 = blockIdx.x * 32, r0 = blockIdx.y * 32;
  int tx = threadIdx.x, ty = threadIdx.y;   // block (32,8)
  for (int i = 0; i < 32; i += 8)
    tile[ty + i][tx] = src[(size_t)(r0 + ty + i) * 3072 + c0 + tx];
  __syncthreads();
  for (int i = 0; i < 32; i += 8) {
    int oc = c0 + ty + i;
    int h = oc / 192, rr = oc % 192;
    int nc = ((rr >> 6) << 10) + (h << 6) + (rr & 63);
    dst[(size_t)nc * 1024 + r0 + tx] = f2bf(tile[tx][ty + i]);
  }
}

// ---------------------------------------------------------------- GEMM core (m97 structure, kept for gemm_out)
#define GEMM_CORE(A_, Bt_)                                                              \
  __shared__ unsigned short As[128 * 32];                                               \
  __shared__ unsigned short Bs[128 * 32];                                               \
  const int tid = threadIdx.x;                                                          \
  const int w = tid >> 6, lane = tid & 63, l15 = lane & 15, quad = lane >> 4;           \
  const int wm = w >> 1, wn = w & 1;                                                    \
  const int col0 = blockIdx.x * 128, row0 = blockIdx.y * 128;                           \
  f32x4 acc[4][4] = {};                                                                 \
  for (int kt = 0; kt < 32; ++kt) {                                                     \
    const int k0 = kt * 32;                                                             \
    for (int p = 0; p < 2; ++p) {                                                       \
      int c = p * 256 + tid;                                                            \
      int m = c >> 2, k8 = (c & 3) * 8;                                                 \
      void* ldsA = (char*)As + (size_t)(p * 256 + (tid & 192)) * 16;                    \
      void* ldsB = (char*)Bs + (size_t)(p * 256 + (tid & 192)) * 16;                    \
      gl_lds16(A_ + (size_t)(row0 + m) * 1024 + k0 + k8, ldsA);                         \
      gl_lds16(Bt_ + (size_t)(col0 + m) * 1024 + k0 + k8, ldsB);                        \
    }                                                                                   \
    __syncthreads();                                                                    \
    bf16x8 af[4], bfr[4];                                                               \
    for (int i = 0; i < 4; ++i)                                                         \
      af[i] = *(const bf16x8*)&As[(wm * 64 + i * 16 + l15) * 32 + quad * 8];            \
    for (int j = 0; j < 4; ++j)                                                         \
      bfr[j] = *(const bf16x8*)&Bs[(wn * 64 + j * 16 + l15) * 32 + quad * 8];           \
    for (int i = 0; i < 4; ++i)                                                         \
      for (int j = 0; j < 4; ++j)                                                       \
        acc[i][j] = MFMA16(af[i], bfr[j], acc[i][j]);                                   \
    __syncthreads();                                                                    \
  }

// ================================================================ gemm_qkv (256x256 8-phase)
// 8-wave (2Mx4N) 256x256 tile, BK=64 split as two 32-col halves, double-buffered
// 128KB LDS, global_load_lds staging with pre-swizzled source (XOR chunk^((row>>1)&3)
// within each 64B LDS row -> 2-way-free ds_read_b128), counted vmcnt(6) at K-tile
// boundaries (loads in flight across raw s_barriers), setprio(1) around MFMA clusters.
// Epilogue identical math to previous version: Q/K -> [bh][s][d] bf16 (Q pre-scaled by
// 0.125*log2e), V -> [bh][d][s], via per-wave 16x66 fp32 LDS transpose (aliased in SH).

#define VM6 asm volatile("s_waitcnt vmcnt(6)" ::: "memory")
#define VM0 asm volatile("s_waitcnt vmcnt(0)" ::: "memory")
#define LGKM0 asm volatile("s_waitcnt lgkmcnt(0)" ::: "memory")
#define BAR __builtin_amdgcn_s_barrier()

// LDS layout (bytes): unit 16384 = one half (256 rows x 32 cols bf16, 64B rows)
//   A-h:  buf*65536 + h*16384
//   B-h:  buf*65536 + 32768 + h*16384
#define STAGE_A(KT, H)                                                           \
  do {                                                                           \
    char* lb_ = SHB + (((KT) & 1) * 65536 + (H) * 16384) + stgo;                 \
    const unsigned short* gs_ = a_src + (KT) * 64 + (H) * 32;                    \
    gl_lds16(gs_, lb_);                                                          \
    gl_lds16(gs_ + 131072, lb_ + 8192);                                          \
  } while (0)
#define STAGE_B(KT, H)                                                           \
  do {                                                                           \
    char* lb_ = SHB + (((KT) & 1) * 65536 + 32768 + (H) * 16384) + stgo;         \
    const unsigned short* gs_ = b_src + (KT) * 64 + (H) * 32;                    \
    gl_lds16(gs_, lb_);                                                          \
    gl_lds16(gs_ + 131072, lb_ + 8192);                                          \
  } while (0)

#define MFMA_BLOCK(MH)                                                           \
  __builtin_amdgcn_s_setprio(1);                                                 \
  acc[(MH)*4+0][0] = MFMA16(af0, bq0, acc[(MH)*4+0][0]);                         \
  acc[(MH)*4+0][1] = MFMA16(af0, bq1, acc[(MH)*4+0][1]);                         \
  acc[(MH)*4+0][2] = MFMA16(af0, bq2, acc[(MH)*4+0][2]);                         \
  acc[(MH)*4+0][3] = MFMA16(af0, bq3, acc[(MH)*4+0][3]);                         \
  acc[(MH)*4+1][0] = MFMA16(af1, bq0, acc[(MH)*4+1][0]);                         \
  acc[(MH)*4+1][1] = MFMA16(af1, bq1, acc[(MH)*4+1][1]);                         \
  acc[(MH)*4+1][2] = MFMA16(af1, bq2, acc[(MH)*4+1][2]);                         \
  acc[(MH)*4+1][3] = MFMA16(af1, bq3, acc[(MH)*4+1][3]);                         \
  acc[(MH)*4+2][0] = MFMA16(af2, bq0, acc[(MH)*4+2][0]);                         \
  acc[(MH)*4+2][1] = MFMA16(af2, bq1, acc[(MH)*4+2][1]);                         \
  acc[(MH)*4+2][2] = MFMA16(af2, bq2, acc[(MH)*4+2][2]);                         \
  acc[(MH)*4+2][3] = MFMA16(af2, bq3, acc[(MH)*4+2][3]);                         \
  acc[(MH)*4+3][0] = MFMA16(af3, bq0, acc[(MH)*4+3][0]);                         \
  acc[(MH)*4+3][1] = MFMA16(af3, bq1, acc[(MH)*4+3][1]);                         \
  acc[(MH)*4+3][2] = MFMA16(af3, bq2, acc[(MH)*4+3][2]);                         \
  acc[(MH)*4+3][3] = MFMA16(af3, bq3, acc[(MH)*4+3][3]);                         \
  __builtin_amdgcn_s_setprio(0)

// 4 phases per K-tile: ks=phase>>1 (K-half), mh=phase&1 (M-half of wave tile).
// Stage schedule (half g=4j+7+p): p0 -> (j+1,B,h1) [other buf, pre-barrier];
// p1 -> (j+2,A,h0), p3 -> (j+2,A,h1) [current buf, issued POST-barrier so every
// wave's same-phase ds_reads of that region are issued first]; p2 -> (j+2,B,h0)
// [current buf, but reads finished last phase -> pre-barrier ok].
#define KTILE(BUF, JT, G0, G2, VMW)                                              \
  {                                                                              \
    { /* phase 0: ks=0 mh=0 */                                                   \
      const char* Ah_ = SHB + (BUF) * 65536;                                     \
      const char* Bh_ = SHB + (BUF) * 65536 + 32768;                             \
      bf16x8 af0 = *(const bf16x8*)(Ah_ + abase);                                \
      bf16x8 af1 = *(const bf16x8*)(Ah_ + abase + 1024);                         \
      bf16x8 af2 = *(const bf16x8*)(Ah_ + abase + 2048);                         \
      bf16x8 af3 = *(const bf16x8*)(Ah_ + abase + 3072);                         \
      bq0 = *(const bf16x8*)(Bh_ + bbase);                                       \
      bq1 = *(const bf16x8*)(Bh_ + bbase + 1024);                                \
      bq2 = *(const bf16x8*)(Bh_ + bbase + 2048);                                \
      bq3 = *(const bf16x8*)(Bh_ + bbase + 3072);                                \
      if (G0) STAGE_B((JT) + 1, 1);                                              \
      BAR;                                                                       \
      LGKM0;                                                                     \
      MFMA_BLOCK(0);                                                             \
      BAR;                                                                       \
    }                                                                            \
    { /* phase 1: ks=0 mh=1 */                                                   \
      const char* Ah_ = SHB + (BUF) * 65536;                                     \
      bf16x8 af0 = *(const bf16x8*)(Ah_ + abase + 4096);                         \
      bf16x8 af1 = *(const bf16x8*)(Ah_ + abase + 5120);                         \
      bf16x8 af2 = *(const bf16x8*)(Ah_ + abase + 6144);                         \
      bf16x8 af3 = *(const bf16x8*)(Ah_ + abase + 7168);                         \
      BAR;                                                                       \
      if (G2) STAGE_A((JT) + 2, 0);                                              \
      LGKM0;                                                                     \
      MFMA_BLOCK(1);                                                             \
      BAR;                                                                       \
    }                                                                            \
    { /* phase 2: ks=1 mh=0 */                                                   \
      const char* Ah_ = SHB + (BUF) * 65536 + 16384;                             \
      const char* Bh_ = SHB + (BUF) * 65536 + 32768 + 16384;                     \
      bf16x8 af0 = *(const bf16x8*)(Ah_ + abase);                                \
      bf16x8 af1 = *(const bf16x8*)(Ah_ + abase + 1024);                         \
      bf16x8 af2 = *(const bf16x8*)(Ah_ + abase + 2048);                         \
      bf16x8 af3 = *(const bf16x8*)(Ah_ + abase + 3072);                         \
      bq0 = *(const bf16x8*)(Bh_ + bbase);                                       \
      bq1 = *(const bf16x8*)(Bh_ + bbase + 1024);                                \
      bq2 = *(const bf16x8*)(Bh_ + bbase + 2048);                                \
      bq3 = *(const bf16x8*)(Bh_ + bbase + 3072);                                \
      if (G2) STAGE_B((JT) + 2, 0);                                              \
      BAR;                                                                       \
      LGKM0;                                                                     \
      MFMA_BLOCK(0);                                                             \
      BAR;                                                                       \
    }                                                                            \
    { /* phase 3: ks=1 mh=1 */                                                   \
      const char* Ah_ = SHB + (BUF) * 65536 + 16384;                             \
      bf16x8 af0 = *(const bf16x8*)(Ah_ + abase + 4096);                         \
      bf16x8 af1 = *(const bf16x8*)(Ah_ + abase + 5120);                         \
      bf16x8 af2 = *(const bf16x8*)(Ah_ + abase + 6144);                         \
      bf16x8 af3 = *(const bf16x8*)(Ah_ + abase + 7168);                         \
      BAR;                                                                       \
      if (G2) STAGE_A((JT) + 2, 1);                                              \
      LGKM0;                                                                     \
      MFMA_BLOCK(1);                                                             \
      VMW;                                                                       \
      BAR;                                                                       \
    }                                                                            \
  }

__global__ __launch_bounds__(512, 2) void gemm_qkv(const unsigned short* __restrict__ A,
                                                   const unsigned short* __restrict__ Bt,
                                                   const float* __restrict__ bias,
                                                   unsigned short* __restrict__ Qb,
                                                   unsigned short* __restrict__ Kb,
                                                   unsigned short* __restrict__ Vtb) {
  __shared__ unsigned short SH[65536];     // 128 KiB: [buf][A/B][khalf][256*32]
  char* SHB = (char*)SH;
  const int tid = threadIdx.x;
  const int w = tid >> 6, lane = tid & 63, l15 = lane & 15, quad = lane >> 4;
  const int wm = w >> 2, wn = w & 3;       // 2M x 4N waves, wave tile 128x64
  // XCD-contiguous swizzle: 384 blocks, 48/XCD chunk, row-major over 12 col-tiles
  const int g = ((blockIdx.x & 7) * 48) + (blockIdx.x >> 3);
  const int bx = g % 12, by = g / 12;
  const int col0 = bx << 8, row0 = by << 8;

  // ds_read swizzle: chunk ^= (row>>1)&3 within the 64B row; for our frag reads
  // (row = base + l15, base multiple of 16) this folds to a per-thread constant.
  const int qa = quad ^ ((l15 >> 1) & 3);
  const int abase = (wm * 128 + l15) * 64 + qa * 16;   // + i*1024 per m-frag
  const int bbase = (wn * 64 + l15) * 64 + qa * 16;    // + j*1024 per n-frag

  // staging: chunk c = p2*512+tid -> LDS byte c*16 (linear); row=c>>2, q'=c&3;
  // source column pre-swizzled: q = q' ^ ((row>>1)&3) = (tid&3)^((tid>>3)&3)
  const int qsw = (tid & 3) ^ ((tid >> 3) & 3);
  const unsigned short* a_src = A + (size_t)(row0 + (tid >> 2)) * 1024 + qsw * 8;
  const unsigned short* b_src = Bt + (size_t)(col0 + (tid >> 2)) * 1024 + qsw * 8;
  const int stgo = (tid & ~63) * 16;       // wave-uniform LDS byte offset

  f32x4 acc[8][4] = {};
  bf16x8 bq0, bq1, bq2, bq3;

  // prologue: K0 {A0,B0,A1,B1} + K1 {A0,B0,A1}; wait K0 complete (6 = K1's 3 halves)
  STAGE_A(0, 0); STAGE_B(0, 0); STAGE_A(0, 1); STAGE_B(0, 1);
  STAGE_A(1, 0); STAGE_B(1, 0); STAGE_A(1, 1);
  VM6;
  BAR;

  #pragma unroll 1
  for (int jj = 0; jj < 8; ++jj) {
    const int j0 = jj * 2;
    const bool more = (jj < 7);
    KTILE(0, j0, 1, more, { if (more) VM6; else VM0; })
    KTILE(1, j0 + 1, more, more, { if (more) VM6; })
  }
  __syncthreads();

  // ---------------- epilogue (same math/layout as previous verified version)
  const int which = col0 >> 10;            // 0=Q, 1=K, 2=V
  const int h = ((col0 + wn * 64) >> 6) & 15;
  const int b = row0 >> 11;
  const int srow0 = (row0 & 2047) + wm * 128;
  float bv[4];
  #pragma unroll
  for (int j = 0; j < 4; ++j) {
    int nc = col0 + wn * 64 + j * 16 + l15;
    int oc = ((nc >> 6) & 15) * 192 + (nc >> 10) * 64 + (nc & 63);
    bv[j] = bias[oc];
  }
  float* Ew = (float*)SHB + w * 1072;      // per-wave 16x66 fp32 tile (aliased in SH)

  if (which < 2) {
    // ---- Q/K: [bh][s][d] row-major, 32B/thread coalesced stores
    const float sc = (which == 0) ? 0.18033688011112042f : 1.0f;  // 1/sqrt(64)*log2e
    const int lr = lane >> 2, d0 = (lane & 3) * 16;
    unsigned short* base = (which == 0 ? Qb : Kb) + ((size_t)(b * 16 + h) * 2048 + srow0) * 64;
    #pragma unroll
    for (int i = 0; i < 8; ++i) {
      #pragma unroll
      for (int j = 0; j < 4; ++j)
        #pragma unroll
        for (int r = 0; r < 4; ++r)
          Ew[(quad * 4 + r) * 66 + j * 16 + l15] = (acc[i][j][r] + bv[j]) * sc;
      float v[16];
      #pragma unroll
      for (int c = 0; c < 4; ++c)
        *(f32x4*)&v[4 * c] = *(const f32x4*)&Ew[lr * 66 + d0 + 4 * c];
      u32x4 pk0 = {pkbf(v[0], v[1]), pkbf(v[2], v[3]), pkbf(v[4], v[5]), pkbf(v[6], v[7])};
      u32x4 pk1 = {pkbf(v[8], v[9]), pkbf(v[10], v[11]), pkbf(v[12], v[13]), pkbf(v[14], v[15])};
      unsigned short* dst = base + (size_t)(i * 16 + lr) * 64 + d0;
      *(u32x4*)dst = pk0;
      *(u32x4*)(dst + 8) = pk1;
    }
  } else {
    // ---- V: transposed [bh][d][s], per-wave column reads (2-way free), 32B stores
    const int d = lane;
    unsigned short* base = Vtb + ((size_t)(b * 16 + h) * 64 + d) * 2048 + srow0;
    #pragma unroll
    for (int i = 0; i < 8; ++i) {
      #pragma unroll
      for (int j = 0; j < 4; ++j)
        #pragma unroll
        for (int r = 0; r < 4; ++r)
          Ew[(quad * 4 + r) * 66 + j * 16 + l15] = acc[i][j][r] + bv[j];
      float e[16];
      #pragma unroll
      for (int k = 0; k < 16; ++k) e[k] = Ew[k * 66 + d];
      u32x4 pk0 = {pkbf(e[0], e[1]), pkbf(e[2], e[3]), pkbf(e[4], e[5]), pkbf(e[6], e[7])};
      u32x4 pk1 = {pkbf(e[8], e[9]), pkbf(e[10], e[11]), pkbf(e[12], e[13]), pkbf(e[14], e[15])};
      unsigned short* dst = base + i * 16;
      *(u32x4*)dst = pk0;
      *(u32x4*)(dst + 8) = pk1;
    }
  }
}

// GEMM2: out = Attn @ Wo + bo (fp32 out). Attn flat [bh][s][d] == reshape quirk layout.
__global__ __launch_bounds__(256) void gemm_out(const unsigned short* __restrict__ A,
                                                const unsigned short* __restrict__ Bt,
                                                const float* __restrict__ bias,
                                                float* __restrict__ out) {
  GEMM_CORE(A, Bt)
  for (int i = 0; i < 4; ++i) {
    int grow = row0 + wm * 64 + i * 16 + quad * 4;
    for (int j = 0; j < 4; ++j) {
      int gcol = col0 + wn * 64 + j * 16 + l15;
      float bvv = bias[gcol];
      for (int r = 0; r < 4; ++r)
        out[(size_t)(grow + r) * 1024 + gcol] = acc[i][j][r] + bvv;
    }
  }
}

// ---------------------------------------------------------------- flash attention (v5)
// 512 blocks, 4 waves x 64 q-rows = 256 q/block. Per 64-key tile, K/V fragment reads
// amortize over 4 sub-tiles (2x MFMA per LDS byte vs v4). Software-pipelined staging.
// Max-free exp2 softmax (Q pre-scaled); l = per-lane VALU partials, reduced once at end.
// Diagonal zone: tile t in 0..3, wave w<t idle, w==t masks, w>t full.
__global__ __launch_bounds__(256) void attn_kernel(const unsigned short* __restrict__ Qb,
                                                   const unsigned short* __restrict__ Kb,
                                                   const unsigned short* __restrict__ Vtb,
                                                   unsigned short* __restrict__ attnout) {
  __shared__ unsigned short K0[64 * 32], K1[64 * 32];   // [k][d<32], [k][d>=32]
  __shared__ unsigned short V0[64 * 32], V1[64 * 32];   // [d][k<32], [d][k>=32]
  __shared__ unsigned short P0[4][4][512], P1[4][4][512]; // per wave/sub, swizzled
  __shared__ float Lbc[4][64];

  const int tid = threadIdx.x;
  const int w = tid >> 6, lane = tid & 63, l15 = lane & 15, quad = lane >> 4;
  // block pairing: qt such that bid and bid+256 sum to 7 (static 2-blocks/CU balance)
  const int i2 = blockIdx.x >> 6;
  const int jj = ((i2 & 1) << 1) | ((i2 >> 1) & 1);
  const int qt = (i2 & 4) ? jj : 7 - jj;
  const int bh = blockIdx.x & 63;
  const int q0w = qt * 256 + w * 64;

  const unsigned short* Qg = Qb + (size_t)bh * S_LEN * DHEAD;
  const unsigned short* Kg = Kb + (size_t)bh * S_LEN * DHEAD;
  const unsigned short* Vg = Vtb + (size_t)bh * DHEAD * S_LEN;

  // Q B-frags (n=q=l15, k=d=quad*8+j), held for whole kernel
  bf16x8 qf[4][2];
  #pragma unroll
  for (int sub = 0; sub < 4; ++sub) {
    const unsigned short* p = Qg + (size_t)(q0w + sub * 16 + l15) * DHEAD + quad * 8;
    qf[sub][0] = *(const bf16x8*)p;
    qf[sub][1] = *(const bf16x8*)(p + 32);
  }

  // staging addresses: thread -> (row = tid>>2, chunk = tid&3)
  const int srow = tid >> 2, sc8 = (tid & 3) * 8;
  const unsigned short* kgb = Kg + srow * 64 + sc8;
  const unsigned short* vgb = Vg + (size_t)srow * S_LEN + sc8;
  const int wKo = srow * 32 + sc8;

  // P swizzle (breaks b64-write conflicts; round-4 proven)
  const int psw = (l15 & 3) ^ ((l15 >> 2) & 3);
  const int pw0 = l15 * 32 + (((quad >> 1) ^ psw) << 3) + ((quad & 1) << 2);
  const int pw1 = l15 * 32 + ((((quad >> 1) + 2) ^ psw) << 3) + ((quad & 1) << 2);
  const int pro = l15 * 32 + ((quad ^ psw) << 3);
  const int kvo = l15 * 32 + quad * 8;

  f32x4 oacc[4][4] = {};
  float lacc[4] = {0.f, 0.f, 0.f, 0.f};

  const int ktdiag = 4 * qt;
  const int nkt = ktdiag + 4;

  // prologue: load tile 0
  bf16x8 kr0 = *(const bf16x8*)kgb, kr1 = *(const bf16x8*)(kgb + 32);
  bf16x8 vr0 = *(const bf16x8*)vgb, vr1 = *(const bf16x8*)(vgb + 32);

  for (int kt = 0; kt < nkt; ++kt) {
    *(bf16x8*)&K0[wKo] = kr0;  *(bf16x8*)&K1[wKo] = kr1;
    *(bf16x8*)&V0[wKo] = vr0;  *(bf16x8*)&V1[wKo] = vr1;
    __syncthreads();
    if (kt + 1 < nkt) {        // prefetch next tile while computing this one
      const unsigned short* kp = kgb + (kt + 1) * 4096;
      const unsigned short* vp = vgb + (kt + 1) * 64;
      kr0 = *(const bf16x8*)kp;  kr1 = *(const bf16x8*)(kp + 32);
      vr0 = *(const bf16x8*)vp;  vr1 = *(const bf16x8*)(vp + 32);
    }

    const int t = kt - ktdiag;              // <0: full zone, 0..3: diagonal zone
    const bool act = (t < 0) || (w >= t);

    if (act) {
      if (t < 0) {
        // ---------------- full tiles (hot path, branch-free)
        #pragma unroll
        for (int jk = 0; jk < 4; ++jk) {
          bf16x8 kf0 = *(const bf16x8*)&K0[jk * 512 + kvo];
          bf16x8 kf1 = *(const bf16x8*)&K1[jk * 512 + kvo];
          #pragma unroll
          for (int sub = 0; sub < 4; ++sub) {
            f32x4 z = {};
            z = MFMA16(kf0, qf[sub][0], z);
            z = MFMA16(kf1, qf[sub][1], z);
            float e0 = __builtin_amdgcn_exp2f(z[0]);
            float e1 = __builtin_amdgcn_exp2f(z[1]);
            float e2 = __builtin_amdgcn_exp2f(z[2]);
            float e3 = __builtin_amdgcn_exp2f(z[3]);
            lacc[sub] += (e0 + e1) + (e2 + e3);
            unsigned short* pd = (jk < 2) ? P0[w][sub] : P1[w][sub];
            *(u32x2*)&pd[(jk & 1) ? pw1 : pw0] = (u32x2){pkbf(e0, e1), pkbf(e2, e3)};
          }
        }
      } else {
        // ---------------- diagonal zone: wave w==t masks, w>t full
        const bool dg = (t == w);
        #pragma unroll
        for (int jk = 0; jk < 4; ++jk) {
          bf16x8 kf0 = *(const bf16x8*)&K0[jk * 512 + kvo];
          bf16x8 kf1 = *(const bf16x8*)&K1[jk * 512 + kvo];
          #pragma unroll
          for (int sub = 0; sub < 4; ++sub) {
            unsigned short* pd = (jk < 2) ? P0[w][sub] : P1[w][sub];
            unsigned int* dst = (unsigned int*)&pd[(jk & 1) ? pw1 : pw0];
            if (dg && jk > sub) { *(u32x2*)dst = (u32x2){0u, 0u}; continue; }
            f32x4 z = {};
            z = MFMA16(kf0, qf[sub][0], z);
            z = MFMA16(kf1, qf[sub][1], z);
            if (dg && jk == sub) {          // diagonal 16x16: mask key > query
              #pragma unroll
              for (int r = 0; r < 4; ++r)
                if (quad * 4 + r > l15) z[r] = -3e38f;
            }
            float e0 = __builtin_amdgcn_exp2f(z[0]);
            float e1 = __builtin_amdgcn_exp2f(z[1]);
            float e2 = __builtin_amdgcn_exp2f(z[2]);
            float e3 = __builtin_amdgcn_exp2f(z[3]);
            lacc[sub] += (e0 + e1) + (e2 + e3);
            *(u32x2*)dst = (u32x2){pkbf(e0, e1), pkbf(e2, e3)};
          }
        }
      }

      // ---- P A-frags, then O += P.V (V B-frags shared across all 4 subs)
      bf16x8 pf[4][2];
      #pragma unroll
      for (int sub = 0; sub < 4; ++sub) {
        pf[sub][0] = *(const bf16x8*)&P0[w][sub][pro];
        pf[sub][1] = *(const bf16x8*)&P1[w][sub][pro];
      }
      #pragma unroll
      for (int dt = 0; dt < 4; ++dt) {
        bf16x8 vb0 = *(const bf16x8*)&V0[dt * 512 + kvo];
        bf16x8 vb1 = *(const bf16x8*)&V1[dt * 512 + kvo];
        #pragma unroll
        for (int sub = 0; sub < 4; ++sub) {
          oacc[sub][dt] = MFMA16(pf[sub][0], vb0, oacc[sub][dt]);
          oacc[sub][dt] = MFMA16(pf[sub][1], vb1, oacc[sub][dt]);
        }
      }
    }
    __syncthreads();
  }

  // ---- finalize: reduce l across quads (once), broadcast via LDS, store
  #pragma unroll
  for (int sub = 0; sub < 4; ++sub) {
    float l = lacc[sub];
    l += __shfl_xor(l, 16);
    l += __shfl_xor(l, 32);
    if (quad == 0) Lbc[w][sub * 16 + l15] = l;
  }
  #pragma unroll
  for (int sub = 0; sub < 4; ++sub) {
    f32x4 l4 = *(const f32x4*)&Lbc[w][sub * 16 + quad * 4];
    int qbase = q0w + sub * 16 + quad * 4;
    unsigned short* dst = attnout + ((size_t)bh * S_LEN + qbase) * DHEAD;
    #pragma unroll
    for (int r = 0; r < 4; ++r) {
      float inv = __builtin_amdgcn_rcpf(l4[r]);
      #pragma unroll
      for (int dt = 0; dt < 4; ++dt)
        dst[(size_t)r * DHEAD + dt * 16 + l15] = f2bf(oacc[sub][dt][r] * inv);
    }
  }
}

// ---------------------------------------------------------------- launch
extern "C" void kernel_launch(void* const* d_in, const int* in_sizes, int n_in,
                              void* d_out, int out_size, void* d_ws, size_t ws_size,
                              hipStream_t stream) {
  const float* x    = (const float*)d_in[0];
  // d_in[1] = mask: deterministic tril, causality applied analytically
  const float* Wqkv = (const float*)d_in[2];
  const float* bqkv = (const float*)d_in[3];
  const float* Wo   = (const float*)d_in[4];
  const float* bo   = (const float*)d_in[5];
  float* out = (float*)d_out;

  char* ws = (char*)d_ws;
  unsigned short* Xbf   = (unsigned short*)(ws);                 // 16 MB
  unsigned short* WqkvT = (unsigned short*)(ws + 16777216);      // 6 MB (permuted)
  unsigned short* WoT   = (unsigned short*)(ws + 23068672);      // 2 MB
  unsigned short* Qb    = (unsigned short*)(ws + 25165824);      // 16.78 MB
  unsigned short* Kb    = (unsigned short*)(ws + 41943040);      // 16.78 MB
  unsigned short* Vtb   = (unsigned short*)(ws + 58720256);      // 16.78 MB  [bh][d][s]
  unsigned short* Attn  = (unsigned short*)(ws + 75497472);      // 16.78 MB

  cast_bf16<<<8192, 256, 0, stream>>>(x, Xbf, MROWS * 1024);
  transpose_cast_qkv<<<dim3(96, 32), dim3(32, 8), 0, stream>>>(Wqkv, WqkvT);
  transpose_cast<<<dim3(32, 32), dim3(32, 8), 0, stream>>>(Wo, WoT, 1024, 1024);
  gemm_qkv<<<384, 512, 0, stream>>>(Xbf, WqkvT, bqkv, Qb, Kb, Vtb);
  attn_kernel<<<512, 256, 0, stream>>>(Qb, Kb, Vtb, Attn);
  gemm_out<<<dim3(8, 64), 256, 0, stream>>>(Attn, WoT, bo, out);
}

// Round 2
// 269.514 us; speedup vs baseline: 1.0075x; 1.0075x over previous
//
#include <hip/hip_runtime.h>

// ---------------------------------------------------------------- types
typedef __attribute__((ext_vector_type(8))) short bf16x8;   // 8 bf16 (4 VGPR)
typedef __attribute__((ext_vector_type(4))) float f32x4;
typedef __attribute__((ext_vector_type(2))) unsigned int u32x2;
typedef __attribute__((ext_vector_type(4))) unsigned int u32x4;

#define MFMA16(a, b, c) __builtin_amdgcn_mfma_f32_16x16x32_bf16((a), (b), (c), 0, 0, 0)

// B=4, S=2048, E=1024, H=16, D=64
#define S_LEN 2048
#define NHEAD 16
#define DHEAD 64
#define BH    64            // B*H
#define MROWS 8192          // B*S

__device__ __forceinline__ unsigned short f2bf(float f) {
  unsigned int u = __builtin_bit_cast(unsigned int, f);
  u += 0x7FFFu + ((u >> 16) & 1u);          // round-to-nearest-even
  return (unsigned short)(u >> 16);
}

__device__ __forceinline__ void gl_lds16(const void* g, void* l) {
  __builtin_amdgcn_global_load_lds(
      (const __attribute__((address_space(1))) void*)g,
      (__attribute__((address_space(3))) void*)l, 16, 0, 0);
}

// pack two fp32 -> (bf16(hi)<<16)|bf16(lo), round-half-up via add+perm
__device__ __forceinline__ unsigned int pkbf(float lo, float hi) {
  unsigned int ulo = __builtin_bit_cast(unsigned int, lo) + 0x8000u;
  unsigned int uhi = __builtin_bit_cast(unsigned int, hi) + 0x8000u;
  return __builtin_amdgcn_perm(uhi, ulo, 0x07060302u);
}

// ---------------------------------------------------------------- cast fp32 -> bf16
__global__ __launch_bounds__(256) void cast_bf16(const float* __restrict__ src,
                                                 unsigned short* __restrict__ dst, int n) {
  int i = (blockIdx.x * 256 + threadIdx.x) * 4;
  if (i + 3 < n) {
    f32x4 v = *(const f32x4*)(src + i);
    unsigned long long pk =
        (unsigned long long)f2bf(v[0]) |
        ((unsigned long long)f2bf(v[1]) << 16) |
        ((unsigned long long)f2bf(v[2]) << 32) |
        ((unsigned long long)f2bf(v[3]) << 48);
    *(unsigned long long*)(dst + i) = pk;
  }
}

// ---------------------------------------------------------------- transpose + cast (plain, for Wo)
__global__ __launch_bounds__(256) void transpose_cast(const float* __restrict__ src,
                                                      unsigned short* __restrict__ dst,
                                                      int R, int C) {
  __shared__ float tile[32][33];
  int c0 = blockIdx.x * 32, r0 = blockIdx.y * 32;
  int tx = threadIdx.x, ty = threadIdx.y;   // block (32,8)
  for (int i = 0; i < 32; i += 8)
    tile[ty + i][tx] = src[(size_t)(r0 + ty + i) * C + c0 + tx];
  __syncthreads();
  for (int i = 0; i < 32; i += 8)
    dst[(size_t)(c0 + ty + i) * R + r0 + tx] = f2bf(tile[tx][ty + i]);
}

// ---------------------------------------------------------------- transpose + cast + col-permute for Wqkv
// src [1024 k][3072 oc], oc = h*192 + which*64 + d  ->  dst[nc][1024], nc = which*1024 + h*64 + d
__global__ __launch_bounds__(256) void transpose_cast_qkv(const float* __restrict__ src,
                                                          unsigned short* __restrict__ dst) {
  __shared__ float tile[32][33];
  int c0 = blockIdx.x * 32, r0 = blockIdx.y * 32;
  int tx = threadIdx.x, ty = threadIdx.y;   // block (32,8)
  for (int i = 0; i < 32; i += 8)
    tile[ty + i][tx] = src[(size_t)(r0 + ty + i) * 3072 + c0 + tx];
  __syncthreads();
  for (int i = 0; i < 32; i += 8) {
    int oc = c0 + ty + i;
    int h = oc / 192, rr = oc % 192;
    int nc = ((rr >> 6) << 10) + (h << 6) + (rr & 63);
    dst[(size_t)nc * 1024 + r0 + tx] = f2bf(tile[tx][ty + i]);
  }
}

// ---------------------------------------------------------------- GEMM core (m97 structure, kept for gemm_out)
#define GEMM_CORE(A_, Bt_)                                                              \
  __shared__ unsigned short As[128 * 32];                                               \
  __shared__ unsigned short Bs[128 * 32];                                               \
  const int tid = threadIdx.x;                                                          \
  const int w = tid >> 6, lane = tid & 63, l15 = lane & 15, quad = lane >> 4;           \
  const int wm = w >> 1, wn = w & 1;                                                    \
  const int col0 = blockIdx.x * 128, row0 = blockIdx.y * 128;                           \
  f32x4 acc[4][4] = {};                                                                 \
  for (int kt = 0; kt < 32; ++kt) {                                                     \
    const int k0 = kt * 32;                                                             \
    for (int p = 0; p < 2; ++p) {                                                       \
      int c = p * 256 + tid;                                                            \
      int m = c >> 2, k8 = (c & 3) * 8;                                                 \
      void* ldsA = (char*)As + (size_t)(p * 256 + (tid & 192)) * 16;                    \
      void* ldsB = (char*)Bs + (size_t)(p * 256 + (tid & 192)) * 16;                    \
      gl_lds16(A_ + (size_t)(row0 + m) * 1024 + k0 + k8, ldsA);                         \
      gl_lds16(Bt_ + (size_t)(col0 + m) * 1024 + k0 + k8, ldsB);                        \
    }                                                                                   \
    __syncthreads();                                                                    \
    bf16x8 af[4], bfr[4];                                                               \
    for (int i = 0; i < 4; ++i)                                                         \
      af[i] = *(const bf16x8*)&As[(wm * 64 + i * 16 + l15) * 32 + quad * 8];            \
    for (int j = 0; j < 4; ++j)                                                         \
      bfr[j] = *(const bf16x8*)&Bs[(wn * 64 + j * 16 + l15) * 32 + quad * 8];           \
    for (int i = 0; i < 4; ++i)                                                         \
      for (int j = 0; j < 4; ++j)                                                       \
        acc[i][j] = MFMA16(af[i], bfr[j], acc[i][j]);                                   \
    for (int __z = 0; __z < 1; ++__z) ;                                                 \
    __syncthreads();                                                                    \
  }

// ================================================================ gemm_qkv (256x256, single-barrier pipelined)
// 8-wave (2Mx4N) 256x256 tile, BK=64 as two 32-col halves, double-buffered 128KB LDS.
// ONE s_barrier per window: {stage; MFMA(p) [auto-lgkm]; ds_reads(p+1); counted vmcnt; bar}
// so one wave's next-window LDS reads overlap other waves' MFMA (the round-1 2-barrier
// version serialized the LDS pipe (~576cy) against the MFMA pipe (~620cy) every phase).
// Derived waits: vmcnt(8) end-of-w0, vmcnt(6) end-of-w2 (tail-corrected 8,4 / 0,- for
// tiles 14/15). All stages target regions whose last reads were consumed before a prior
// barrier (strictly safe). sched_barrier(0) pins window boundaries.

#define VM8 asm volatile("s_waitcnt vmcnt(8)" ::: "memory")
#define VM6 asm volatile("s_waitcnt vmcnt(6)" ::: "memory")
#define VM4 asm volatile("s_waitcnt vmcnt(4)" ::: "memory")
#define VM0 asm volatile("s_waitcnt vmcnt(0)" ::: "memory")
#define VMNOP ((void)0)
#define BAR __builtin_amdgcn_s_barrier()
#define SB  __builtin_amdgcn_sched_barrier(0)

// LDS layout (bytes): unit 16384 = one half (256 rows x 32 cols bf16, 64B rows)
//   A-h:  buf*65536 + h*16384        B-h: buf*65536 + 32768 + h*16384
#define STAGE_A(KT, H)                                                           \
  do {                                                                           \
    char* lb_ = SHB + (((KT) & 1) * 65536 + (H) * 16384) + stgo;                 \
    const unsigned short* gs_ = a_src + (KT) * 64 + (H) * 32;                    \
    gl_lds16(gs_, lb_);                                                          \
    gl_lds16(gs_ + 131072, lb_ + 8192);                                          \
  } while (0)
#define STAGE_B(KT, H)                                                           \
  do {                                                                           \
    char* lb_ = SHB + (((KT) & 1) * 65536 + 32768 + (H) * 16384) + stgo;         \
    const unsigned short* gs_ = b_src + (KT) * 64 + (H) * 32;                    \
    gl_lds16(gs_, lb_);                                                          \
    gl_lds16(gs_ + 131072, lb_ + 8192);                                          \
  } while (0)

#define MFMA_BLK(A0,A1,A2,A3, B0,B1,B2,B3, MH)                                   \
  __builtin_amdgcn_s_setprio(1);                                                 \
  acc[(MH)*4+0][0] = MFMA16(A0, B0, acc[(MH)*4+0][0]);                           \
  acc[(MH)*4+0][1] = MFMA16(A0, B1, acc[(MH)*4+0][1]);                           \
  acc[(MH)*4+0][2] = MFMA16(A0, B2, acc[(MH)*4+0][2]);                           \
  acc[(MH)*4+0][3] = MFMA16(A0, B3, acc[(MH)*4+0][3]);                           \
  acc[(MH)*4+1][0] = MFMA16(A1, B0, acc[(MH)*4+1][0]);                           \
  acc[(MH)*4+1][1] = MFMA16(A1, B1, acc[(MH)*4+1][1]);                           \
  acc[(MH)*4+1][2] = MFMA16(A1, B2, acc[(MH)*4+1][2]);                           \
  acc[(MH)*4+1][3] = MFMA16(A1, B3, acc[(MH)*4+1][3]);                           \
  acc[(MH)*4+2][0] = MFMA16(A2, B0, acc[(MH)*4+2][0]);                           \
  acc[(MH)*4+2][1] = MFMA16(A2, B1, acc[(MH)*4+2][1]);                           \
  acc[(MH)*4+2][2] = MFMA16(A2, B2, acc[(MH)*4+2][2]);                           \
  acc[(MH)*4+2][3] = MFMA16(A2, B3, acc[(MH)*4+2][3]);                           \
  acc[(MH)*4+3][0] = MFMA16(A3, B0, acc[(MH)*4+3][0]);                           \
  acc[(MH)*4+3][1] = MFMA16(A3, B1, acc[(MH)*4+3][1]);                           \
  acc[(MH)*4+3][2] = MFMA16(A3, B2, acc[(MH)*4+3][2]);                           \
  acc[(MH)*4+3][3] = MFMA16(A3, B3, acc[(MH)*4+3][3]);                           \
  __builtin_amdgcn_s_setprio(0)

#define RD4(D0,D1,D2,D3, P)                                                      \
  D0 = *(const bf16x8*)((P));                                                    \
  D1 = *(const bf16x8*)((P) + 1024);                                             \
  D2 = *(const bf16x8*)((P) + 2048);                                             \
  D3 = *(const bf16x8*)((P) + 3072)

// One K-tile = 4 single-barrier windows.
// Frag reg sets: phases p0/p2 consume afA, p1/p3 consume afB; p0/p1 use bqA (kh0),
// p2/p3 use bqB (kh1). Reads for phase p are issued in window p-1.
#define KT1(BUF, JT, G1, G2, RDN, VMA_, VMB_)                                    \
  { /* w0: stage (JT+1)kh1; MFMA(afA,bqA,mh0); rd afB <- A kh0 hi */             \
    if (G1) { STAGE_A((JT)+1, 1); STAGE_B((JT)+1, 1); }                          \
    MFMA_BLK(afA0,afA1,afA2,afA3, bqA0,bqA1,bqA2,bqA3, 0);                       \
    RD4(afB0,afB1,afB2,afB3, SHB + (BUF)*65536 + abase + 4096);                  \
    VMA_; SB; BAR; SB;                                                           \
  }                                                                              \
  { /* w1: MFMA(afB,bqA,mh1); rd afA <- A kh1 lo, bqB <- B kh1 */                \
    MFMA_BLK(afB0,afB1,afB2,afB3, bqA0,bqA1,bqA2,bqA3, 1);                       \
    RD4(afA0,afA1,afA2,afA3, SHB + (BUF)*65536 + 16384 + abase);                 \
    RD4(bqB0,bqB1,bqB2,bqB3, SHB + (BUF)*65536 + 49152 + bbase);                 \
    SB; BAR; SB;                                                                 \
  }                                                                              \
  { /* w2: stage (JT+2)A-kh0; MFMA(afA,bqB,mh0); rd afB <- A kh1 hi */           \
    if (G2) STAGE_A((JT)+2, 0);                                                  \
    MFMA_BLK(afA0,afA1,afA2,afA3, bqB0,bqB1,bqB2,bqB3, 0);                       \
    RD4(afB0,afB1,afB2,afB3, SHB + (BUF)*65536 + 16384 + abase + 4096);          \
    VMB_; SB; BAR; SB;                                                           \
  }                                                                              \
  { /* w3: stage (JT+2)B-kh0; MFMA(afB,bqB,mh1); rd next afA,bqA */              \
    if (G2) STAGE_B((JT)+2, 0);                                                  \
    MFMA_BLK(afB0,afB1,afB2,afB3, bqB0,bqB1,bqB2,bqB3, 1);                       \
    if (RDN) {                                                                   \
      RD4(afA0,afA1,afA2,afA3, SHB + (1-(BUF))*65536 + abase);                   \
      RD4(bqA0,bqA1,bqA2,bqA3, SHB + (1-(BUF))*65536 + 32768 + bbase);           \
    }                                                                            \
    SB; BAR; SB;                                                                 \
  }

__global__ __launch_bounds__(512, 2) void gemm_qkv(const unsigned short* __restrict__ A,
                                                   const unsigned short* __restrict__ Bt,
                                                   const float* __restrict__ bias,
                                                   unsigned short* __restrict__ Qb,
                                                   unsigned short* __restrict__ Kb,
                                                   unsigned short* __restrict__ Vtb) {
  __shared__ unsigned short SH[65536];     // 128 KiB: [buf][A/B][khalf][256*32]
  char* SHB = (char*)SH;
  const int tid = threadIdx.x;
  const int w = tid >> 6, lane = tid & 63, l15 = lane & 15, quad = lane >> 4;
  const int wm = w >> 2, wn = w & 3;       // 2M x 4N waves, wave tile 128x64
  // XCD-contiguous swizzle: 384 blocks, 48/XCD chunk, row-major over 12 col-tiles
  const int g = ((blockIdx.x & 7) * 48) + (blockIdx.x >> 3);
  const int bx = g % 12, by = g / 12;
  const int col0 = bx << 8, row0 = by << 8;

  // ds_read swizzle: chunk ^= (row>>1)&3 within the 64B row
  const int qa = quad ^ ((l15 >> 1) & 3);
  const int abase = (wm * 128 + l15) * 64 + qa * 16;   // + i*1024 per m-frag
  const int bbase = (wn * 64 + l15) * 64 + qa * 16;    // + j*1024 per n-frag

  // staging: thread c -> LDS byte c*16 (linear); source column pre-swizzled
  const int qsw = (tid & 3) ^ ((tid >> 3) & 3);
  const unsigned short* a_src = A + (size_t)(row0 + (tid >> 2)) * 1024 + qsw * 8;
  const unsigned short* b_src = Bt + (size_t)(col0 + (tid >> 2)) * 1024 + qsw * 8;
  const int stgo = (tid & ~63) * 16;       // wave-uniform LDS byte offset

  f32x4 acc[8][4] = {};
  bf16x8 afA0, afA1, afA2, afA3, afB0, afB1, afB2, afB3;
  bf16x8 bqA0, bqA1, bqA2, bqA3, bqB0, bqB1, bqB2, bqB3;

  // prologue: tile0 all 4 halves + tile1 kh0; wait own first 4 loads, barrier,
  // then first frag reads (cross-wave safe: after every wave's VM8+BAR)
  STAGE_A(0, 0); STAGE_B(0, 0); STAGE_A(0, 1); STAGE_B(0, 1);
  STAGE_A(1, 0); STAGE_B(1, 0);
  VM8; SB; BAR; SB;
  RD4(afA0, afA1, afA2, afA3, SHB + abase);
  RD4(bqA0, bqA1, bqA2, bqA3, SHB + 32768 + bbase);

  #pragma unroll 1
  for (int jj = 0; jj < 7; ++jj) {
    const int j0 = 2 * jj;
    KT1(0, j0,     1, 1, 1, VM8, VM6)
    KT1(1, j0 + 1, 1, 1, 1, VM8, VM6)
  }
  // tail: tile 14 (no j+2 stages; vmcnt counts corrected), tile 15 (drain)
  KT1(0, 14, 1, 0, 1, VM8, VM4)
  KT1(1, 15, 0, 0, 0, VM0, VMNOP)
  VM0;
  __syncthreads();

  // ---------------- epilogue (same math/layout as previous verified version)
  const int which = col0 >> 10;            // 0=Q, 1=K, 2=V
  const int h = ((col0 + wn * 64) >> 6) & 15;
  const int b = row0 >> 11;
  const int srow0 = (row0 & 2047) + wm * 128;
  float bv[4];
  #pragma unroll
  for (int j = 0; j < 4; ++j) {
    int nc = col0 + wn * 64 + j * 16 + l15;
    int oc = ((nc >> 6) & 15) * 192 + (nc >> 10) * 64 + (nc & 63);
    bv[j] = bias[oc];
  }
  float* Ew = (float*)SHB + w * 1072;      // per-wave 16x66 fp32 tile (aliased in SH)

  if (which < 2) {
    // ---- Q/K: [bh][s][d] row-major, 32B/thread coalesced stores
    const float sc = (which == 0) ? 0.18033688011112042f : 1.0f;  // 1/sqrt(64)*log2e
    const int lr = lane >> 2, d0 = (lane & 3) * 16;
    unsigned short* base = (which == 0 ? Qb : Kb) + ((size_t)(b * 16 + h) * 2048 + srow0) * 64;
    #pragma unroll
    for (int i = 0; i < 8; ++i) {
      #pragma unroll
      for (int j = 0; j < 4; ++j)
        #pragma unroll
        for (int r = 0; r < 4; ++r)
          Ew[(quad * 4 + r) * 66 + j * 16 + l15] = (acc[i][j][r] + bv[j]) * sc;
      float v[16];
      #pragma unroll
      for (int c = 0; c < 4; ++c)
        *(f32x4*)&v[4 * c] = *(const f32x4*)&Ew[lr * 66 + d0 + 4 * c];
      u32x4 pk0 = {pkbf(v[0], v[1]), pkbf(v[2], v[3]), pkbf(v[4], v[5]), pkbf(v[6], v[7])};
      u32x4 pk1 = {pkbf(v[8], v[9]), pkbf(v[10], v[11]), pkbf(v[12], v[13]), pkbf(v[14], v[15])};
      unsigned short* dst = base + (size_t)(i * 16 + lr) * 64 + d0;
      *(u32x4*)dst = pk0;
      *(u32x4*)(dst + 8) = pk1;
    }
  } else {
    // ---- V: transposed [bh][d][s], per-wave column reads (2-way free), 32B stores
    const int d = lane;
    unsigned short* base = Vtb + ((size_t)(b * 16 + h) * 64 + d) * 2048 + srow0;
    #pragma unroll
    for (int i = 0; i < 8; ++i) {
      #pragma unroll
      for (int j = 0; j < 4; ++j)
        #pragma unroll
        for (int r = 0; r < 4; ++r)
          Ew[(quad * 4 + r) * 66 + j * 16 + l15] = acc[i][j][r] + bv[j];
      float e[16];
      #pragma unroll
      for (int k = 0; k < 16; ++k) e[k] = Ew[k * 66 + d];
      u32x4 pk0 = {pkbf(e[0], e[1]), pkbf(e[2], e[3]), pkbf(e[4], e[5]), pkbf(e[6], e[7])};
      u32x4 pk1 = {pkbf(e[8], e[9]), pkbf(e[10], e[11]), pkbf(e[12], e[13]), pkbf(e[14], e[15])};
      unsigned short* dst = base + i * 16;
      *(u32x4*)dst = pk0;
      *(u32x4*)(dst + 8) = pk1;
    }
  }
}

// GEMM2: out = Attn @ Wo + bo (fp32 out). Attn flat [bh][s][d] == reshape quirk layout.
__global__ __launch_bounds__(256) void gemm_out(const unsigned short* __restrict__ A,
                                                const unsigned short* __restrict__ Bt,
                                                const float* __restrict__ bias,
                                                float* __restrict__ out) {
  GEMM_CORE(A, Bt)
  for (int i = 0; i < 4; ++i) {
    int grow = row0 + wm * 64 + i * 16 + quad * 4;
    for (int j = 0; j < 4; ++j) {
      int gcol = col0 + wn * 64 + j * 16 + l15;
      float bvv = bias[gcol];
      for (int r = 0; r < 4; ++r)
        out[(size_t)(grow + r) * 1024 + gcol] = acc[i][j][r] + bvv;
    }
  }
}

// ---------------------------------------------------------------- flash attention (v5)
// 512 blocks, 4 waves x 64 q-rows = 256 q/block. Per 64-key tile, K/V fragment reads
// amortize over 4 sub-tiles (2x MFMA per LDS byte vs v4). Software-pipelined staging.
// Max-free exp2 softmax (Q pre-scaled); l = per-lane VALU partials, reduced once at end.
// Diagonal zone: tile t in 0..3, wave w<t idle, w==t masks, w>t full.
__global__ __launch_bounds__(256) void attn_kernel(const unsigned short* __restrict__ Qb,
                                                   const unsigned short* __restrict__ Kb,
                                                   const unsigned short* __restrict__ Vtb,
                                                   unsigned short* __restrict__ attnout) {
  __shared__ unsigned short K0[64 * 32], K1[64 * 32];   // [k][d<32], [k][d>=32]
  __shared__ unsigned short V0[64 * 32], V1[64 * 32];   // [d][k<32], [d][k>=32]
  __shared__ unsigned short P0[4][4][512], P1[4][4][512]; // per wave/sub, swizzled
  __shared__ float Lbc[4][64];

  const int tid = threadIdx.x;
  const int w = tid >> 6, lane = tid & 63, l15 = lane & 15, quad = lane >> 4;
  // block pairing: qt such that bid and bid+256 sum to 7 (static 2-blocks/CU balance)
  const int i2 = blockIdx.x >> 6;
  const int jj = ((i2 & 1) << 1) | ((i2 >> 1) & 1);
  const int qt = (i2 & 4) ? jj : 7 - jj;
  const int bh = blockIdx.x & 63;
  const int q0w = qt * 256 + w * 64;

  const unsigned short* Qg = Qb + (size_t)bh * S_LEN * DHEAD;
  const unsigned short* Kg = Kb + (size_t)bh * S_LEN * DHEAD;
  const unsigned short* Vg = Vtb + (size_t)bh * DHEAD * S_LEN;

  // Q B-frags (n=q=l15, k=d=quad*8+j), held for whole kernel
  bf16x8 qf[4][2];
  #pragma unroll
  for (int sub = 0; sub < 4; ++sub) {
    const unsigned short* p = Qg + (size_t)(q0w + sub * 16 + l15) * DHEAD + quad * 8;
    qf[sub][0] = *(const bf16x8*)p;
    qf[sub][1] = *(const bf16x8*)(p + 32);
  }

  // staging addresses: thread -> (row = tid>>2, chunk = tid&3)
  const int srow = tid >> 2, sc8 = (tid & 3) * 8;
  const unsigned short* kgb = Kg + srow * 64 + sc8;
  const unsigned short* vgb = Vg + (size_t)srow * S_LEN + sc8;
  const int wKo = srow * 32 + sc8;

  // P swizzle (breaks b64-write conflicts; round-4 proven)
  const int psw = (l15 & 3) ^ ((l15 >> 2) & 3);
  const int pw0 = l15 * 32 + (((quad >> 1) ^ psw) << 3) + ((quad & 1) << 2);
  const int pw1 = l15 * 32 + ((((quad >> 1) + 2) ^ psw) << 3) + ((quad & 1) << 2);
  const int pro = l15 * 32 + ((quad ^ psw) << 3);
  const int kvo = l15 * 32 + quad * 8;

  f32x4 oacc[4][4] = {};
  float lacc[4] = {0.f, 0.f, 0.f, 0.f};

  const int ktdiag = 4 * qt;
  const int nkt = ktdiag + 4;

  // prologue: load tile 0
  bf16x8 kr0 = *(const bf16x8*)kgb, kr1 = *(const bf16x8*)(kgb + 32);
  bf16x8 vr0 = *(const bf16x8*)vgb, vr1 = *(const bf16x8*)(vgb + 32);

  for (int kt = 0; kt < nkt; ++kt) {
    *(bf16x8*)&K0[wKo] = kr0;  *(bf16x8*)&K1[wKo] = kr1;
    *(bf16x8*)&V0[wKo] = vr0;  *(bf16x8*)&V1[wKo] = vr1;
    __syncthreads();
    if (kt + 1 < nkt) {        // prefetch next tile while computing this one
      const unsigned short* kp = kgb + (kt + 1) * 4096;
      const unsigned short* vp = vgb + (kt + 1) * 64;
      kr0 = *(const bf16x8*)kp;  kr1 = *(const bf16x8*)(kp + 32);
      vr0 = *(const bf16x8*)vp;  vr1 = *(const bf16x8*)(vp + 32);
    }

    const int t = kt - ktdiag;              // <0: full zone, 0..3: diagonal zone
    const bool act = (t < 0) || (w >= t);

    if (act) {
      if (t < 0) {
        // ---------------- full tiles (hot path, branch-free)
        #pragma unroll
        for (int jk = 0; jk < 4; ++jk) {
          bf16x8 kf0 = *(const bf16x8*)&K0[jk * 512 + kvo];
          bf16x8 kf1 = *(const bf16x8*)&K1[jk * 512 + kvo];
          #pragma unroll
          for (int sub = 0; sub < 4; ++sub) {
            f32x4 z = {};
            z = MFMA16(kf0, qf[sub][0], z);
            z = MFMA16(kf1, qf[sub][1], z);
            float e0 = __builtin_amdgcn_exp2f(z[0]);
            float e1 = __builtin_amdgcn_exp2f(z[1]);
            float e2 = __builtin_amdgcn_exp2f(z[2]);
            float e3 = __builtin_amdgcn_exp2f(z[3]);
            lacc[sub] += (e0 + e1) + (e2 + e3);
            unsigned short* pd = (jk < 2) ? P0[w][sub] : P1[w][sub];
            *(u32x2*)&pd[(jk & 1) ? pw1 : pw0] = (u32x2){pkbf(e0, e1), pkbf(e2, e3)};
          }
        }
      } else {
        // ---------------- diagonal zone: wave w==t masks, w>t full
        const bool dg = (t == w);
        #pragma unroll
        for (int jk = 0; jk < 4; ++jk) {
          bf16x8 kf0 = *(const bf16x8*)&K0[jk * 512 + kvo];
          bf16x8 kf1 = *(const bf16x8*)&K1[jk * 512 + kvo];
          #pragma unroll
          for (int sub = 0; sub < 4; ++sub) {
            unsigned short* pd = (jk < 2) ? P0[w][sub] : P1[w][sub];
            unsigned int* dst = (unsigned int*)&pd[(jk & 1) ? pw1 : pw0];
            if (dg && jk > sub) { *(u32x2*)dst = (u32x2){0u, 0u}; continue; }
            f32x4 z = {};
            z = MFMA16(kf0, qf[sub][0], z);
            z = MFMA16(kf1, qf[sub][1], z);
            if (dg && jk == sub) {          // diagonal 16x16: mask key > query
              #pragma unroll
              for (int r = 0; r < 4; ++r)
                if (quad * 4 + r > l15) z[r] = -3e38f;
            }
            float e0 = __builtin_amdgcn_exp2f(z[0]);
            float e1 = __builtin_amdgcn_exp2f(z[1]);
            float e2 = __builtin_amdgcn_exp2f(z[2]);
            float e3 = __builtin_amdgcn_exp2f(z[3]);
            lacc[sub] += (e0 + e1) + (e2 + e3);
            *(u32x2*)dst = (u32x2){pkbf(e0, e1), pkbf(e2, e3)};
          }
        }
      }

      // ---- P A-frags, then O += P.V (V B-frags shared across all 4 subs)
      bf16x8 pf[4][2];
      #pragma unroll
      for (int sub = 0; sub < 4; ++sub) {
        pf[sub][0] = *(const bf16x8*)&P0[w][sub][pro];
        pf[sub][1] = *(const bf16x8*)&P1[w][sub][pro];
      }
      #pragma unroll
      for (int dt = 0; dt < 4; ++dt) {
        bf16x8 vb0 = *(const bf16x8*)&V0[dt * 512 + kvo];
        bf16x8 vb1 = *(const bf16x8*)&V1[dt * 512 + kvo];
        #pragma unroll
        for (int sub = 0; sub < 4; ++sub) {
          oacc[sub][dt] = MFMA16(pf[sub][0], vb0, oacc[sub][dt]);
          oacc[sub][dt] = MFMA16(pf[sub][1], vb1, oacc[sub][dt]);
        }
      }
    }
    __syncthreads();
  }

  // ---- finalize: reduce l across quads (once), broadcast via LDS, store
  #pragma unroll
  for (int sub = 0; sub < 4; ++sub) {
    float l = lacc[sub];
    l += __shfl_xor(l, 16);
    l += __shfl_xor(l, 32);
    if (quad == 0) Lbc[w][sub * 16 + l15] = l;
  }
  #pragma unroll
  for (int sub = 0; sub < 4; ++sub) {
    f32x4 l4 = *(const f32x4*)&Lbc[w][sub * 16 + quad * 4];
    int qbase = q0w + sub * 16 + quad * 4;
    unsigned short* dst = attnout + ((size_t)bh * S_LEN + qbase) * DHEAD;
    #pragma unroll
    for (int r = 0; r < 4; ++r) {
      float inv = __builtin_amdgcn_rcpf(l4[r]);
      #pragma unroll
      for (int dt = 0; dt < 4; ++dt)
        dst[(size_t)r * DHEAD + dt * 16 + l15] = f2bf(oacc[sub][dt][r] * inv);
    }
  }
}

// ---------------------------------------------------------------- launch
extern "C" void kernel_launch(void* const* d_in, const int* in_sizes, int n_in,
                              void* d_out, int out_size, void* d_ws, size_t ws_size,
                              hipStream_t stream) {
  const float* x    = (const float*)d_in[0];
  // d_in[1] = mask: deterministic tril, causality applied analytically
  const float* Wqkv = (const float*)d_in[2];
  const float* bqkv = (const float*)d_in[3];
  const float* Wo   = (const float*)d_in[4];
  const float* bo   = (const float*)d_in[5];
  float* out = (float*)d_out;

  char* ws = (char*)d_ws;
  unsigned short* Xbf   = (unsigned short*)(ws);                 // 16 MB
  unsigned short* WqkvT = (unsigned short*)(ws + 16777216);      // 6 MB (permuted)
  unsigned short* WoT   = (unsigned short*)(ws + 23068672);      // 2 MB
  unsigned short* Qb    = (unsigned short*)(ws + 25165824);      // 16.78 MB
  unsigned short* Kb    = (unsigned short*)(ws + 41943040);      // 16.78 MB
  unsigned short* Vtb   = (unsigned short*)(ws + 58720256);      // 16.78 MB  [bh][d][s]
  unsigned short* Attn  = (unsigned short*)(ws + 75497472);      // 16.78 MB

  cast_bf16<<<8192, 256, 0, stream>>>(x, Xbf, MROWS * 1024);
  transpose_cast_qkv<<<dim3(96, 32), dim3(32, 8), 0, stream>>>(Wqkv, WqkvT);
  transpose_cast<<<dim3(32, 32), dim3(32, 8), 0, stream>>>(Wo, WoT, 1024, 1024);
  gemm_qkv<<<384, 512, 0, stream>>>(Xbf, WqkvT, bqkv, Qb, Kb, Vtb);
  attn_kernel<<<512, 256, 0, stream>>>(Qb, Kb, Vtb, Attn);
  gemm_out<<<dim3(8, 64), 256, 0, stream>>>(Attn, WoT, bo, out);
}